// Round 9
// baseline (926.421 us; speedup 1.0000x reference)
//
#include <hip/hip_runtime.h>
#include <hip/hip_fp16.h>

#define NNODES   100000
#define NFEAT    16
#define NEDGES   3200000
#define EH       1600000     // edges per half
#define NB       250         // dst buckets
#define NODES_PB 400         // 250*400 = 100000
#define NCH      125         // chunks per half
#define CHK      12800       // 125*12800 = 1600000
#define CAP      7680        // per-bucket-half capacity (mean 6400, sigma~80 -> +16s)

#define NTL(p)    __builtin_nontemporal_load(p)
#define NTS(v, p) __builtin_nontemporal_store(v, p)

// ---------- K1: per-chunk bucket histogram over one half ----------
__global__ __launch_bounds__(1024) void hist_chunk(
    const int* __restrict__ dst, int ebase, int* __restrict__ cnt /*[NCH][NB]*/)
{
    __shared__ int h[NB];
    int c = blockIdx.x;
    for (int i = threadIdx.x; i < NB; i += 1024) h[i] = 0;
    __syncthreads();
    int base = ebase + c * CHK;
    for (int i = threadIdx.x; i < CHK; i += 1024) {
        int d = NTL(dst + base + i);
        atomicAdd(&h[d / NODES_PB], 1);
    }
    __syncthreads();
    for (int i = threadIdx.x; i < NB; i += 1024) cnt[c * NB + i] = h[i];
}

// ---------- K2: per-bucket exclusive scan over chunks ----------
__global__ __launch_bounds__(256) void scan_chunks(
    int* __restrict__ cnt, int* __restrict__ tot)
{
    __shared__ int x[256];
    int b = blockIdx.x, t = threadIdx.x;
    int v = (t < NCH) ? cnt[t * NB + b] : 0;
    x[t] = v;
    __syncthreads();
    for (int off = 1; off < 256; off <<= 1) {
        int y = (t >= off) ? x[t - off] : 0;
        __syncthreads();
        x[t] += y;
        __syncthreads();
    }
    if (t < NCH) cnt[t * NB + b] = x[t] - v;
    if (t == NCH - 1) tot[b] = x[t];
}

// ---------- K3: exclusive scan of bucket totals -> bb[NB+1] ----------
__global__ __launch_bounds__(256) void scan_tot(
    const int* __restrict__ tot, int* __restrict__ bb)
{
    __shared__ int x[256];
    int t = threadIdx.x;
    int v = (t < NB) ? tot[t] : 0;
    x[t] = v;
    __syncthreads();
    for (int off = 1; off < 256; off <<= 1) {
        int y = (t >= off) ? x[t - off] : 0;
        __syncthreads();
        x[t] += y;
        __syncthreads();
    }
    if (t < NB) bb[t] = x[t] - v;
    if (t == NB - 1) bb[NB] = x[t];
}

// ---------- K4: scatter edges of one half into bucket-major AoS slots ----------
// entry = 3 dwords: {src | dl<<17, half2(w0,w1), half2(w2,w3)}
__global__ __launch_bounds__(1024) void scatter_bins(
    const int*   __restrict__ src,
    const int*   __restrict__ dst,
    const float* __restrict__ wt,
    const float* __restrict__ lw,
    int ebase,
    const int*   __restrict__ cnt,
    const int*   __restrict__ bb,
    unsigned int* __restrict__ binsE)
{
    __shared__ int cur[NB];
    int c = blockIdx.x;
    for (int i = threadIdx.x; i < NB; i += 1024)
        cur[i] = bb[i] + cnt[c * NB + i];
    __syncthreads();
    int base = ebase + c * CHK;
    for (int i = threadIdx.x; i < CHK; i += 1024) {
        int e = base + i;
        int d = NTL(dst + e);
        int b  = d / NODES_PB;
        int dl = d - b * NODES_PB;
        float w = NTL(wt + e);
        float l0 = NTL(lw + e);
        float l1 = NTL(lw + NEDGES + e);
        float l2 = NTL(lw + 2 * NEDGES + e);
        float l3 = NTL(lw + 3 * NEDGES + e);
        int s = NTL(src + e);
        __half2 w01 = __floats2half2_rn(w * l0, w * l1);
        __half2 w23 = __floats2half2_rn(w * l2, w * l3);
        int slot = atomicAdd(&cur[b], 1);
        unsigned int* p = binsE + 3u * (unsigned int)slot;
        NTS((unsigned int)s | ((unsigned int)dl << 17), p);
        NTS(*(const unsigned int*)&w01, p + 1);
        NTS(*(const unsigned int*)&w23, p + 2);
    }
}

// ---------- K5: per-bucket node sort -> csrA + 4 f16 planes + offs ----------
__global__ __launch_bounds__(512) void bucket_csr(
    const int*          __restrict__ bb,
    const unsigned int* __restrict__ binsE,
    unsigned int*       __restrict__ csrA,
    unsigned short*     __restrict__ w0,    // f16 bit patterns
    unsigned short*     __restrict__ w1,
    unsigned short*     __restrict__ w2,
    unsigned short*     __restrict__ w3,
    int*                __restrict__ offs)
{
    __shared__ unsigned int sA[CAP];     // 30720 B
    __shared__ int hist[NODES_PB];
    __shared__ int cur[NODES_PB];
    __shared__ int sc[512];              // total ~36 KB -> 4 blocks/CU
    int b  = blockIdx.x, t = threadIdx.x;
    int e0 = bb[b];
    int cnt = bb[b + 1] - e0;
    if (cnt > CAP) cnt = CAP;            // statistically impossible; guards corruption

    for (int i = t; i < NODES_PB; i += 512) hist[i] = 0;
    __syncthreads();
    for (int i = t; i < cnt; i += 512) {
        unsigned int a = NTL(binsE + 3u * (unsigned int)(e0 + i));
        sA[i] = a;
        atomicAdd(&hist[a >> 17], 1);
    }
    __syncthreads();
    int v = (t < NODES_PB) ? hist[t] : 0;
    sc[t] = v;
    __syncthreads();
    for (int off = 1; off < 512; off <<= 1) {
        int y = (t >= off) ? sc[t - off] : 0;
        __syncthreads();
        sc[t] += y;
        __syncthreads();
    }
    if (t < NODES_PB) {
        int excl = sc[t] - v;
        cur[t] = excl;
        offs[b * NODES_PB + t] = e0 + excl;
    }
    if (b == 0 && t == 0) offs[NNODES] = EH;
    __syncthreads();
    for (int i = t; i < cnt; i += 512) {
        unsigned int a = sA[i];
        int slot = atomicAdd(&cur[a >> 17], 1);
        int p = e0 + slot;
        unsigned int u01 = NTL(binsE + 3u * (unsigned int)(e0 + i) + 1);
        unsigned int u23 = NTL(binsE + 3u * (unsigned int)(e0 + i) + 2);
        NTS(a & 0x1FFFFu, csrA + p);
        NTS((unsigned short)(u01 & 0xFFFFu),  w0 + p);
        NTS((unsigned short)(u01 >> 16),      w1 + p);
        NTS((unsigned short)(u23 & 0xFFFFu),  w2 + p);
        NTS((unsigned short)(u23 >> 16),      w3 + p);
    }
}

// ---------- K6: pull layer (16 lanes/node, reg accumulate, two halves) ----------
// Streaming reads (csrA, wk) are non-temporal so the 3.2 MB f16 h table
// stays L2-resident; gathers (hin) use normal cached loads.
template<bool IN16>
__device__ __forceinline__ float seg_acc(
    int j, int j1, const unsigned int* __restrict__ csrA,
    const unsigned short* __restrict__ wku, const void* __restrict__ hin,
    int f, float acc)
{
    const __half* h16 = (const __half*)hin;
    const float*  h32 = (const float*)hin;
    for (; j + 1 < j1; j += 2) {
        unsigned int s0 = NTL(csrA + j), s1 = NTL(csrA + j + 1);
        unsigned short wa_u = NTL(wku + j);
        unsigned short wb_u = NTL(wku + j + 1);
        float wa = __half2float(__ushort_as_half(wa_u));
        float wb = __half2float(__ushort_as_half(wb_u));
        float v0 = IN16 ? __half2float(h16[s0 * NFEAT + f]) : h32[s0 * NFEAT + f];
        float v1 = IN16 ? __half2float(h16[s1 * NFEAT + f]) : h32[s1 * NFEAT + f];
        acc = fmaf(wa, v0, acc);
        acc = fmaf(wb, v1, acc);
    }
    if (j < j1) {
        unsigned int s0 = NTL(csrA + j);
        unsigned short wa_u = NTL(wku + j);
        float wa = __half2float(__ushort_as_half(wa_u));
        float v0 = IN16 ? __half2float(h16[s0 * NFEAT + f]) : h32[s0 * NFEAT + f];
        acc = fmaf(wa, v0, acc);
    }
    return acc;
}

template<bool IN16, bool SIG>
__global__ __launch_bounds__(256) void pull16(
    const int*            __restrict__ offs1,
    const int*            __restrict__ offs2,
    const unsigned int*   __restrict__ csrA1,
    const unsigned int*   __restrict__ csrA2,
    const unsigned short* __restrict__ wk1,
    const unsigned short* __restrict__ wk2,
    const void*           __restrict__ hin,
    const float*          __restrict__ h0,
    void*                 __restrict__ hout)
{
    int t = blockIdx.x * 256 + threadIdx.x;
    int n = t >> 4;
    if (n >= NNODES) return;
    int f = t & 15;
    float acc = 0.f;
    acc = seg_acc<IN16>(offs1[n], offs1[n + 1], csrA1, wk1, hin, f, acc);
    acc = seg_acc<IN16>(offs2[n], offs2[n + 1], csrA2, wk2, hin, f, acc);
    int o = n * NFEAT + f;
    if (SIG) {
        float r = 1.f / (1.f + expf(-2.f * acc));
        NTS(r, (float*)hout + o);
    } else {
        unsigned short rb = __half_as_ushort(__float2half_rn(acc + h0[o]));
        ((unsigned short*)hout)[o] = rb;
    }
}

// ---------------- fallback (atomic push path, needs only 6.4 MB ws) ----------------
__global__ __launch_bounds__(256) void scatter_layer(
    const int* __restrict__ src, const int* __restrict__ dst,
    const float* __restrict__ wt, const float* __restrict__ lw,
    const float* __restrict__ h, float* __restrict__ acc)
{
    long t = (long)blockIdx.x * blockDim.x + threadIdx.x;
    int e = (int)(t >> 4);
    if (e >= NEDGES) return;
    int f = (int)(t & 15);
    float w = wt[e] * lw[e];
    atomicAdd(&acc[dst[e] * NFEAT + f], w * h[src[e] * NFEAT + f]);
}
__global__ __launch_bounds__(256) void sigmoid_inplace(float* __restrict__ out, int n)
{
    int i = blockIdx.x * blockDim.x + threadIdx.x;
    if (i < n) out[i] = 1.f / (1.f + expf(-2.f * out[i]));
}

// ---------------- launch ----------------
extern "C" void kernel_launch(void* const* d_in, const int* in_sizes, int n_in,
                              void* d_out, int out_size, void* d_ws, size_t ws_size,
                              hipStream_t stream)
{
    const float* h0 = (const float*)d_in[0];
    const int*   ei = (const int*)d_in[1];     // int32 (JAX x64 off)
    const float* wt = (const float*)d_in[2];
    const float* lw = (const float*)d_in[3];

    const int* src = ei;
    const int* dst = ei + NEDGES;

    // workspace layout (bytes)
    const size_t off_cnt   = 0;                                 // int[125*250]
    const size_t off_tot   = 125056;
    const size_t off_bb    = 126080;
    const size_t off_offs1 = 127104;                            // int[100001]
    const size_t off_offs2 = off_offs1 + 400128;
    const size_t off_csrA  = off_offs2 + 400128;                // u32[2*EH]   12.8 MB
    const size_t off_w     = off_csrA + (size_t)2 * EH * 4;     // f16[8*EH]   25.6 MB
    const size_t off_bins  = off_w + (size_t)8 * EH * 2;        // u32[3*EH]   19.2 MB
    const size_t need      = off_bins + (size_t)3 * EH * 4;     // ~58.5 MB

    if (ws_size < need) {
        const size_t hbytes = (size_t)NNODES * NFEAT * sizeof(float);
        float* hw = (float*)d_ws;
        float* ho = (float*)d_out;
        dim3 blk(256), grd(((long)NEDGES * 16 + 255) / 256);
        hipMemcpyAsync(hw, h0, hbytes, hipMemcpyDeviceToDevice, stream);
        scatter_layer<<<grd, blk, 0, stream>>>(src, dst, wt, lw + 0L * NEDGES, h0, hw);
        hipMemcpyAsync(ho, h0, hbytes, hipMemcpyDeviceToDevice, stream);
        scatter_layer<<<grd, blk, 0, stream>>>(src, dst, wt, lw + 1L * NEDGES, hw, ho);
        hipMemcpyAsync(hw, h0, hbytes, hipMemcpyDeviceToDevice, stream);
        scatter_layer<<<grd, blk, 0, stream>>>(src, dst, wt, lw + 2L * NEDGES, ho, hw);
        hipMemsetAsync(ho, 0, hbytes, stream);
        scatter_layer<<<grd, blk, 0, stream>>>(src, dst, wt, lw + 3L * NEDGES, hw, ho);
        int n = NNODES * NFEAT;
        sigmoid_inplace<<<(n + 255) / 256, 256, 0, stream>>>(ho, n);
        return;
    }

    char* ws = (char*)d_ws;
    int*            cnt   = (int*)(ws + off_cnt);
    int*            tot   = (int*)(ws + off_tot);
    int*            bb    = (int*)(ws + off_bb);
    int*            offs1 = (int*)(ws + off_offs1);
    int*            offs2 = (int*)(ws + off_offs2);
    unsigned int*   csrA1 = (unsigned int*)(ws + off_csrA);
    unsigned int*   csrA2 = csrA1 + EH;
    unsigned short* wbase = (unsigned short*)(ws + off_w);
    unsigned short* w0_1 = wbase + 0L * EH; unsigned short* w1_1 = wbase + 1L * EH;
    unsigned short* w2_1 = wbase + 2L * EH; unsigned short* w3_1 = wbase + 3L * EH;
    unsigned short* w0_2 = wbase + 4L * EH; unsigned short* w1_2 = wbase + 5L * EH;
    unsigned short* w2_2 = wbase + 6L * EH; unsigned short* w3_2 = wbase + 7L * EH;
    unsigned int*   binsE = (unsigned int*)(ws + off_bins);
    __half*         hbA   = (__half*)(ws + off_bins);                  // alias dead bins
    __half*         hbB   = (__half*)(ws + off_bins + (size_t)NNODES * NFEAT * 2);
    float*          hout  = (float*)d_out;

    // ---- build: two independent halves ----
    // half 1
    hist_chunk  <<<NCH, 1024, 0, stream>>>(dst, 0, cnt);
    scan_chunks <<<NB,   256, 0, stream>>>(cnt, tot);
    scan_tot    <<<1,    256, 0, stream>>>(tot, bb);
    scatter_bins<<<NCH, 1024, 0, stream>>>(src, dst, wt, lw, 0, cnt, bb, binsE);
    bucket_csr  <<<NB,   512, 0, stream>>>(bb, binsE, csrA1, w0_1, w1_1, w2_1, w3_1, offs1);
    // half 2
    hist_chunk  <<<NCH, 1024, 0, stream>>>(dst, EH, cnt);
    scan_chunks <<<NB,   256, 0, stream>>>(cnt, tot);
    scan_tot    <<<1,    256, 0, stream>>>(tot, bb);
    scatter_bins<<<NCH, 1024, 0, stream>>>(src, dst, wt, lw, EH, cnt, bb, binsE);
    bucket_csr  <<<NB,   512, 0, stream>>>(bb, binsE, csrA2, w0_2, w1_2, w2_2, w3_2, offs2);

    // ---- 4 pull layers ----
    dim3 blk(256), grd((NNODES * 16) / 256);
    pull16<false, false><<<grd, blk, 0, stream>>>(offs1, offs2, csrA1, csrA2, w0_1, w0_2, h0,  h0, hbA);
    pull16<true,  false><<<grd, blk, 0, stream>>>(offs1, offs2, csrA1, csrA2, w1_1, w1_2, hbA, h0, hbB);
    pull16<true,  false><<<grd, blk, 0, stream>>>(offs1, offs2, csrA1, csrA2, w2_1, w2_2, hbB, h0, hbA);
    pull16<true,  true ><<<grd, blk, 0, stream>>>(offs1, offs2, csrA1, csrA2, w3_1, w3_2, hbA, h0, hout);
}

// Round 10
// 544.694 us; speedup vs baseline: 1.7008x; 1.7008x over previous
//
#include <hip/hip_runtime.h>
#include <hip/hip_fp16.h>

#define NNODES   100000
#define NFEAT    16
#define NEDGES   3200000
#define EH       1600000     // edges per half
#define NB       250         // dst buckets
#define NODES_PB 400         // 250*400 = 100000
#define NCH      125         // chunks per half
#define CHK      12800       // 125*12800 = 1600000
#define CAP      7680        // per-bucket-half capacity (mean 6400, sigma~80 -> +16s)

#define NTL(p)    __builtin_nontemporal_load(p)
#define NTS(v, p) __builtin_nontemporal_store(v, p)

// ---------- K1: per-chunk bucket histogram over one half ----------
__global__ __launch_bounds__(1024) void hist_chunk(
    const int* __restrict__ dst, int ebase, int* __restrict__ cnt /*[NCH][NB]*/)
{
    __shared__ int h[NB];
    int c = blockIdx.x;
    for (int i = threadIdx.x; i < NB; i += 1024) h[i] = 0;
    __syncthreads();
    int base = ebase + c * CHK;
    for (int i = threadIdx.x; i < CHK; i += 1024) {
        int d = NTL(dst + base + i);
        atomicAdd(&h[d / NODES_PB], 1);
    }
    __syncthreads();
    for (int i = threadIdx.x; i < NB; i += 1024) cnt[c * NB + i] = h[i];
}

// ---------- K2: per-bucket exclusive scan over chunks ----------
__global__ __launch_bounds__(256) void scan_chunks(
    int* __restrict__ cnt, int* __restrict__ tot)
{
    __shared__ int x[256];
    int b = blockIdx.x, t = threadIdx.x;
    int v = (t < NCH) ? cnt[t * NB + b] : 0;
    x[t] = v;
    __syncthreads();
    for (int off = 1; off < 256; off <<= 1) {
        int y = (t >= off) ? x[t - off] : 0;
        __syncthreads();
        x[t] += y;
        __syncthreads();
    }
    if (t < NCH) cnt[t * NB + b] = x[t] - v;
    if (t == NCH - 1) tot[b] = x[t];
}

// ---------- K3: exclusive scan of bucket totals -> bb[NB+1] ----------
__global__ __launch_bounds__(256) void scan_tot(
    const int* __restrict__ tot, int* __restrict__ bb)
{
    __shared__ int x[256];
    int t = threadIdx.x;
    int v = (t < NB) ? tot[t] : 0;
    x[t] = v;
    __syncthreads();
    for (int off = 1; off < 256; off <<= 1) {
        int y = (t >= off) ? x[t - off] : 0;
        __syncthreads();
        x[t] += y;
        __syncthreads();
    }
    if (t < NB) bb[t] = x[t] - v;
    if (t == NB - 1) bb[NB] = x[t];
}

// ---------- K4: scatter edges of one half into bucket-major AoS slots ----------
// entry = 3 dwords: {src | dl<<17, half2(w0,w1), half2(w2,w3)}
// Scattered stores are NORMAL (L2-coalesced); nt loads on the streams.
__global__ __launch_bounds__(1024) void scatter_bins(
    const int*   __restrict__ src,
    const int*   __restrict__ dst,
    const float* __restrict__ wt,
    const float* __restrict__ lw,
    int ebase,
    const int*   __restrict__ cnt,
    const int*   __restrict__ bb,
    unsigned int* __restrict__ binsE)
{
    __shared__ int cur[NB];
    int c = blockIdx.x;
    for (int i = threadIdx.x; i < NB; i += 1024)
        cur[i] = bb[i] + cnt[c * NB + i];
    __syncthreads();
    int base = ebase + c * CHK;
    for (int i = threadIdx.x; i < CHK; i += 1024) {
        int e = base + i;
        int d = NTL(dst + e);
        int b  = d / NODES_PB;
        int dl = d - b * NODES_PB;
        float w = NTL(wt + e);
        float l0 = NTL(lw + e);
        float l1 = NTL(lw + NEDGES + e);
        float l2 = NTL(lw + 2 * NEDGES + e);
        float l3 = NTL(lw + 3 * NEDGES + e);
        int s = NTL(src + e);
        __half2 w01 = __floats2half2_rn(w * l0, w * l1);
        __half2 w23 = __floats2half2_rn(w * l2, w * l3);
        int slot = atomicAdd(&cur[b], 1);
        unsigned int* p = binsE + 3u * (unsigned int)slot;
        p[0] = (unsigned int)s | ((unsigned int)dl << 17);
        p[1] = *(const unsigned int*)&w01;
        p[2] = *(const unsigned int*)&w23;
    }
}

// ---------- K5: per-bucket node sort -> csrA + 4 f16 planes + offs ----------
// Scattered stores NORMAL; sequential binsE reads non-temporal.
__global__ __launch_bounds__(512) void bucket_csr(
    const int*          __restrict__ bb,
    const unsigned int* __restrict__ binsE,
    unsigned int*       __restrict__ csrA,
    unsigned short*     __restrict__ w0,    // f16 bit patterns
    unsigned short*     __restrict__ w1,
    unsigned short*     __restrict__ w2,
    unsigned short*     __restrict__ w3,
    int*                __restrict__ offs)
{
    __shared__ unsigned int sA[CAP];     // 30720 B
    __shared__ int hist[NODES_PB];
    __shared__ int cur[NODES_PB];
    __shared__ int sc[512];              // total ~36 KB -> 4 blocks/CU
    int b  = blockIdx.x, t = threadIdx.x;
    int e0 = bb[b];
    int cnt = bb[b + 1] - e0;
    if (cnt > CAP) cnt = CAP;            // statistically impossible; guards corruption

    for (int i = t; i < NODES_PB; i += 512) hist[i] = 0;
    __syncthreads();
    for (int i = t; i < cnt; i += 512) {
        unsigned int a = NTL(binsE + 3u * (unsigned int)(e0 + i));
        sA[i] = a;
        atomicAdd(&hist[a >> 17], 1);
    }
    __syncthreads();
    int v = (t < NODES_PB) ? hist[t] : 0;
    sc[t] = v;
    __syncthreads();
    for (int off = 1; off < 512; off <<= 1) {
        int y = (t >= off) ? sc[t - off] : 0;
        __syncthreads();
        sc[t] += y;
        __syncthreads();
    }
    if (t < NODES_PB) {
        int excl = sc[t] - v;
        cur[t] = excl;
        offs[b * NODES_PB + t] = e0 + excl;
    }
    if (b == 0 && t == 0) offs[NNODES] = EH;
    __syncthreads();
    for (int i = t; i < cnt; i += 512) {
        unsigned int a = sA[i];
        int slot = atomicAdd(&cur[a >> 17], 1);
        int p = e0 + slot;
        unsigned int u01 = NTL(binsE + 3u * (unsigned int)(e0 + i) + 1);
        unsigned int u23 = NTL(binsE + 3u * (unsigned int)(e0 + i) + 2);
        csrA[p] = a & 0x1FFFFu;
        w0[p] = (unsigned short)(u01 & 0xFFFFu);
        w1[p] = (unsigned short)(u01 >> 16);
        w2[p] = (unsigned short)(u23 & 0xFFFFu);
        w3[p] = (unsigned short)(u23 >> 16);
    }
}

// ---------- K6: pull layer (16 lanes/node, reg accumulate, two halves) ----------
// Streaming reads (csrA, wk) are non-temporal so the 3.2 MB f16 h table
// stays L2-resident; gathers (hin) use normal cached loads.
template<bool IN16>
__device__ __forceinline__ float seg_acc(
    int j, int j1, const unsigned int* __restrict__ csrA,
    const unsigned short* __restrict__ wku, const void* __restrict__ hin,
    int f, float acc)
{
    const __half* h16 = (const __half*)hin;
    const float*  h32 = (const float*)hin;
    for (; j + 1 < j1; j += 2) {
        unsigned int s0 = NTL(csrA + j), s1 = NTL(csrA + j + 1);
        unsigned short wa_u = NTL(wku + j);
        unsigned short wb_u = NTL(wku + j + 1);
        float wa = __half2float(__ushort_as_half(wa_u));
        float wb = __half2float(__ushort_as_half(wb_u));
        float v0 = IN16 ? __half2float(h16[s0 * NFEAT + f]) : h32[s0 * NFEAT + f];
        float v1 = IN16 ? __half2float(h16[s1 * NFEAT + f]) : h32[s1 * NFEAT + f];
        acc = fmaf(wa, v0, acc);
        acc = fmaf(wb, v1, acc);
    }
    if (j < j1) {
        unsigned int s0 = NTL(csrA + j);
        unsigned short wa_u = NTL(wku + j);
        float wa = __half2float(__ushort_as_half(wa_u));
        float v0 = IN16 ? __half2float(h16[s0 * NFEAT + f]) : h32[s0 * NFEAT + f];
        acc = fmaf(wa, v0, acc);
    }
    return acc;
}

template<bool IN16, bool SIG>
__global__ __launch_bounds__(256) void pull16(
    const int*            __restrict__ offs1,
    const int*            __restrict__ offs2,
    const unsigned int*   __restrict__ csrA1,
    const unsigned int*   __restrict__ csrA2,
    const unsigned short* __restrict__ wk1,
    const unsigned short* __restrict__ wk2,
    const void*           __restrict__ hin,
    const float*          __restrict__ h0,
    void*                 __restrict__ hout)
{
    int t = blockIdx.x * 256 + threadIdx.x;
    int n = t >> 4;
    if (n >= NNODES) return;
    int f = t & 15;
    float acc = 0.f;
    acc = seg_acc<IN16>(offs1[n], offs1[n + 1], csrA1, wk1, hin, f, acc);
    acc = seg_acc<IN16>(offs2[n], offs2[n + 1], csrA2, wk2, hin, f, acc);
    int o = n * NFEAT + f;
    if (SIG) {
        float r = 1.f / (1.f + expf(-2.f * acc));
        NTS(r, (float*)hout + o);    // sequential full-line final output
    } else {
        ((unsigned short*)hout)[o] = __half_as_ushort(__float2half_rn(acc + h0[o]));
    }
}

// ---------------- fallback (atomic push path, needs only 6.4 MB ws) ----------------
__global__ __launch_bounds__(256) void scatter_layer(
    const int* __restrict__ src, const int* __restrict__ dst,
    const float* __restrict__ wt, const float* __restrict__ lw,
    const float* __restrict__ h, float* __restrict__ acc)
{
    long t = (long)blockIdx.x * blockDim.x + threadIdx.x;
    int e = (int)(t >> 4);
    if (e >= NEDGES) return;
    int f = (int)(t & 15);
    float w = wt[e] * lw[e];
    atomicAdd(&acc[dst[e] * NFEAT + f], w * h[src[e] * NFEAT + f]);
}
__global__ __launch_bounds__(256) void sigmoid_inplace(float* __restrict__ out, int n)
{
    int i = blockIdx.x * blockDim.x + threadIdx.x;
    if (i < n) out[i] = 1.f / (1.f + expf(-2.f * out[i]));
}

// ---------------- launch ----------------
extern "C" void kernel_launch(void* const* d_in, const int* in_sizes, int n_in,
                              void* d_out, int out_size, void* d_ws, size_t ws_size,
                              hipStream_t stream)
{
    const float* h0 = (const float*)d_in[0];
    const int*   ei = (const int*)d_in[1];     // int32 (JAX x64 off)
    const float* wt = (const float*)d_in[2];
    const float* lw = (const float*)d_in[3];

    const int* src = ei;
    const int* dst = ei + NEDGES;

    // workspace layout (bytes)
    const size_t off_cnt   = 0;                                 // int[125*250]
    const size_t off_tot   = 125056;
    const size_t off_bb    = 126080;
    const size_t off_offs1 = 127104;                            // int[100001]
    const size_t off_offs2 = off_offs1 + 400128;
    const size_t off_csrA  = off_offs2 + 400128;                // u32[2*EH]   12.8 MB
    const size_t off_w     = off_csrA + (size_t)2 * EH * 4;     // f16[8*EH]   25.6 MB
    const size_t off_bins  = off_w + (size_t)8 * EH * 2;        // u32[3*EH]   19.2 MB
    const size_t need      = off_bins + (size_t)3 * EH * 4;     // ~58.5 MB

    if (ws_size < need) {
        const size_t hbytes = (size_t)NNODES * NFEAT * sizeof(float);
        float* hw = (float*)d_ws;
        float* ho = (float*)d_out;
        dim3 blk(256), grd(((long)NEDGES * 16 + 255) / 256);
        hipMemcpyAsync(hw, h0, hbytes, hipMemcpyDeviceToDevice, stream);
        scatter_layer<<<grd, blk, 0, stream>>>(src, dst, wt, lw + 0L * NEDGES, h0, hw);
        hipMemcpyAsync(ho, h0, hbytes, hipMemcpyDeviceToDevice, stream);
        scatter_layer<<<grd, blk, 0, stream>>>(src, dst, wt, lw + 1L * NEDGES, hw, ho);
        hipMemcpyAsync(hw, h0, hbytes, hipMemcpyDeviceToDevice, stream);
        scatter_layer<<<grd, blk, 0, stream>>>(src, dst, wt, lw + 2L * NEDGES, ho, hw);
        hipMemsetAsync(ho, 0, hbytes, stream);
        scatter_layer<<<grd, blk, 0, stream>>>(src, dst, wt, lw + 3L * NEDGES, hw, ho);
        int n = NNODES * NFEAT;
        sigmoid_inplace<<<(n + 255) / 256, 256, 0, stream>>>(ho, n);
        return;
    }

    char* ws = (char*)d_ws;
    int*            cnt   = (int*)(ws + off_cnt);
    int*            tot   = (int*)(ws + off_tot);
    int*            bb    = (int*)(ws + off_bb);
    int*            offs1 = (int*)(ws + off_offs1);
    int*            offs2 = (int*)(ws + off_offs2);
    unsigned int*   csrA1 = (unsigned int*)(ws + off_csrA);
    unsigned int*   csrA2 = csrA1 + EH;
    unsigned short* wbase = (unsigned short*)(ws + off_w);
    unsigned short* w0_1 = wbase + 0L * EH; unsigned short* w1_1 = wbase + 1L * EH;
    unsigned short* w2_1 = wbase + 2L * EH; unsigned short* w3_1 = wbase + 3L * EH;
    unsigned short* w0_2 = wbase + 4L * EH; unsigned short* w1_2 = wbase + 5L * EH;
    unsigned short* w2_2 = wbase + 6L * EH; unsigned short* w3_2 = wbase + 7L * EH;
    unsigned int*   binsE = (unsigned int*)(ws + off_bins);
    __half*         hbA   = (__half*)(ws + off_bins);                  // alias dead bins
    __half*         hbB   = (__half*)(ws + off_bins + (size_t)NNODES * NFEAT * 2);
    float*          hout  = (float*)d_out;

    // ---- build: two independent halves ----
    // half 1
    hist_chunk  <<<NCH, 1024, 0, stream>>>(dst, 0, cnt);
    scan_chunks <<<NB,   256, 0, stream>>>(cnt, tot);
    scan_tot    <<<1,    256, 0, stream>>>(tot, bb);
    scatter_bins<<<NCH, 1024, 0, stream>>>(src, dst, wt, lw, 0, cnt, bb, binsE);
    bucket_csr  <<<NB,   512, 0, stream>>>(bb, binsE, csrA1, w0_1, w1_1, w2_1, w3_1, offs1);
    // half 2
    hist_chunk  <<<NCH, 1024, 0, stream>>>(dst, EH, cnt);
    scan_chunks <<<NB,   256, 0, stream>>>(cnt, tot);
    scan_tot    <<<1,    256, 0, stream>>>(tot, bb);
    scatter_bins<<<NCH, 1024, 0, stream>>>(src, dst, wt, lw, EH, cnt, bb, binsE);
    bucket_csr  <<<NB,   512, 0, stream>>>(bb, binsE, csrA2, w0_2, w1_2, w2_2, w3_2, offs2);

    // ---- 4 pull layers ----
    dim3 blk(256), grd((NNODES * 16) / 256);
    pull16<false, false><<<grd, blk, 0, stream>>>(offs1, offs2, csrA1, csrA2, w0_1, w0_2, h0,  h0, hbA);
    pull16<true,  false><<<grd, blk, 0, stream>>>(offs1, offs2, csrA1, csrA2, w1_1, w1_2, hbA, h0, hbB);
    pull16<true,  false><<<grd, blk, 0, stream>>>(offs1, offs2, csrA1, csrA2, w2_1, w2_2, hbB, h0, hbA);
    pull16<true,  true ><<<grd, blk, 0, stream>>>(offs1, offs2, csrA1, csrA2, w3_1, w3_2, hbA, h0, hout);
}

// Round 11
// 373.528 us; speedup vs baseline: 2.4802x; 1.4582x over previous
//
#include <hip/hip_runtime.h>
#include <hip/hip_fp16.h>

#define NNODES   100000
#define NFEAT    16
#define NEDGES   3200000
#define EH       1600000     // edges per half
#define NB       250         // dst buckets
#define NODES_PB 400         // 250*400 = 100000
#define NCH      125         // chunks per half
#define CHK      12800       // 125*12800 = 1600000
#define CAP      7680        // per-bucket-half capacity (mean 6400, sigma~80 -> +16s)

// ---------- K1: per-chunk bucket histogram over one half ----------
__global__ __launch_bounds__(1024) void hist_chunk(
    const int* __restrict__ dst, int ebase, int* __restrict__ cnt /*[NCH][NB]*/)
{
    __shared__ int h[NB];
    int c = blockIdx.x;
    for (int i = threadIdx.x; i < NB; i += 1024) h[i] = 0;
    __syncthreads();
    int base = ebase + c * CHK;
    for (int i = threadIdx.x; i < CHK; i += 1024) {
        int d = dst[base + i];
        atomicAdd(&h[d / NODES_PB], 1);
    }
    __syncthreads();
    for (int i = threadIdx.x; i < NB; i += 1024) cnt[c * NB + i] = h[i];
}

// ---------- K2: per-bucket exclusive scan over chunks ----------
__global__ __launch_bounds__(256) void scan_chunks(
    int* __restrict__ cnt, int* __restrict__ tot)
{
    __shared__ int x[256];
    int b = blockIdx.x, t = threadIdx.x;
    int v = (t < NCH) ? cnt[t * NB + b] : 0;
    x[t] = v;
    __syncthreads();
    for (int off = 1; off < 256; off <<= 1) {
        int y = (t >= off) ? x[t - off] : 0;
        __syncthreads();
        x[t] += y;
        __syncthreads();
    }
    if (t < NCH) cnt[t * NB + b] = x[t] - v;
    if (t == NCH - 1) tot[b] = x[t];
}

// ---------- K3: exclusive scan of bucket totals -> bb[NB+1] ----------
__global__ __launch_bounds__(256) void scan_tot(
    const int* __restrict__ tot, int* __restrict__ bb)
{
    __shared__ int x[256];
    int t = threadIdx.x;
    int v = (t < NB) ? tot[t] : 0;
    x[t] = v;
    __syncthreads();
    for (int off = 1; off < 256; off <<= 1) {
        int y = (t >= off) ? x[t - off] : 0;
        __syncthreads();
        x[t] += y;
        __syncthreads();
    }
    if (t < NB) bb[t] = x[t] - v;
    if (t == NB - 1) bb[NB] = x[t];
}

// ---------- K4: scatter edges of one half into bucket-major AoS slots ----------
// entry = 3 dwords: {src | dl<<17, half2(w0,w1), half2(w2,w3)}
__global__ __launch_bounds__(1024) void scatter_bins(
    const int*   __restrict__ src,
    const int*   __restrict__ dst,
    const float* __restrict__ wt,
    const float* __restrict__ lw,
    int ebase,
    const int*   __restrict__ cnt,
    const int*   __restrict__ bb,
    unsigned int* __restrict__ binsE)
{
    __shared__ int cur[NB];
    int c = blockIdx.x;
    for (int i = threadIdx.x; i < NB; i += 1024)
        cur[i] = bb[i] + cnt[c * NB + i];
    __syncthreads();
    int base = ebase + c * CHK;
    for (int i = threadIdx.x; i < CHK; i += 1024) {
        int e = base + i;
        int d = dst[e];
        int b  = d / NODES_PB;
        int dl = d - b * NODES_PB;
        float w = wt[e];
        __half2 w01 = __floats2half2_rn(w * lw[e],              w * lw[NEDGES + e]);
        __half2 w23 = __floats2half2_rn(w * lw[2 * NEDGES + e], w * lw[3 * NEDGES + e]);
        int slot = atomicAdd(&cur[b], 1);
        unsigned int* p = binsE + 3u * (unsigned int)slot;
        p[0] = (unsigned int)src[e] | ((unsigned int)dl << 17);
        p[1] = *(const unsigned int*)&w01;
        p[2] = *(const unsigned int*)&w23;
    }
}

// ---------- K5: per-bucket node sort -> csrA + 4 f16 planes + offs ----------
__global__ __launch_bounds__(512) void bucket_csr(
    const int*          __restrict__ bb,
    const unsigned int* __restrict__ binsE,
    unsigned int*       __restrict__ csrA,
    unsigned short*     __restrict__ w0,    // f16 bit patterns
    unsigned short*     __restrict__ w1,
    unsigned short*     __restrict__ w2,
    unsigned short*     __restrict__ w3,
    int*                __restrict__ offs)
{
    __shared__ unsigned int sA[CAP];     // 30720 B
    __shared__ int hist[NODES_PB];
    __shared__ int cur[NODES_PB];
    __shared__ int sc[512];              // total ~36 KB -> 4 blocks/CU
    int b  = blockIdx.x, t = threadIdx.x;
    int e0 = bb[b];
    int cnt = bb[b + 1] - e0;
    if (cnt > CAP) cnt = CAP;            // statistically impossible; guards corruption

    for (int i = t; i < NODES_PB; i += 512) hist[i] = 0;
    __syncthreads();
    for (int i = t; i < cnt; i += 512) {
        unsigned int a = binsE[3u * (unsigned int)(e0 + i)];
        sA[i] = a;
        atomicAdd(&hist[a >> 17], 1);
    }
    __syncthreads();
    int v = (t < NODES_PB) ? hist[t] : 0;
    sc[t] = v;
    __syncthreads();
    for (int off = 1; off < 512; off <<= 1) {
        int y = (t >= off) ? sc[t - off] : 0;
        __syncthreads();
        sc[t] += y;
        __syncthreads();
    }
    if (t < NODES_PB) {
        int excl = sc[t] - v;
        cur[t] = excl;
        offs[b * NODES_PB + t] = e0 + excl;
    }
    if (b == 0 && t == 0) offs[NNODES] = EH;
    __syncthreads();
    for (int i = t; i < cnt; i += 512) {
        unsigned int a = sA[i];
        int slot = atomicAdd(&cur[a >> 17], 1);
        int p = e0 + slot;
        unsigned int u01 = binsE[3u * (unsigned int)(e0 + i) + 1];
        unsigned int u23 = binsE[3u * (unsigned int)(e0 + i) + 2];
        csrA[p] = a & 0x1FFFFu;
        w0[p] = (unsigned short)(u01 & 0xFFFFu);
        w1[p] = (unsigned short)(u01 >> 16);
        w2[p] = (unsigned short)(u23 & 0xFFFFu);
        w3[p] = (unsigned short)(u23 >> 16);
    }
}

// ---------- helpers ----------
template<bool IN16>
__device__ __forceinline__ float hval(const void* __restrict__ hin, unsigned int s, int f)
{
    if (IN16) return __half2float(((const __half*)hin)[s * NFEAT + f]);
    else      return ((const float*)hin)[s * NFEAT + f];
}

template<bool IN16>
__device__ __forceinline__ float seg_acc(
    int j, int j1, const unsigned int* __restrict__ csrA,
    const unsigned short* __restrict__ wku, const void* __restrict__ hin,
    int f, float acc)
{
    for (; j + 1 < j1; j += 2) {
        unsigned int s0 = csrA[j], s1 = csrA[j + 1];
        float wa = __half2float(__ushort_as_half(wku[j]));
        float wb = __half2float(__ushort_as_half(wku[j + 1]));
        float v0 = hval<IN16>(hin, s0, f);
        float v1 = hval<IN16>(hin, s1, f);
        acc = fmaf(wa, v0, acc);
        acc = fmaf(wb, v1, acc);
    }
    if (j < j1) {
        unsigned int s0 = csrA[j];
        float wa = __half2float(__ushort_as_half(wku[j]));
        acc = fmaf(wa, hval<IN16>(hin, s0, f), acc);
    }
    return acc;
}

// ---------- K6: pull layer — both halves interleaved: 4 independent chains ----------
template<bool IN16, bool SIG>
__global__ __launch_bounds__(256) void pull16(
    const int*            __restrict__ offs1,
    const int*            __restrict__ offs2,
    const unsigned int*   __restrict__ csrA1,
    const unsigned int*   __restrict__ csrA2,
    const unsigned short* __restrict__ wk1,
    const unsigned short* __restrict__ wk2,
    const void*           __restrict__ hin,
    const float*          __restrict__ h0,
    void*                 __restrict__ hout)
{
    int t = blockIdx.x * 256 + threadIdx.x;
    int n = t >> 4;
    if (n >= NNODES) return;
    int f = t & 15;
    int j1 = offs1[n], e1 = offs1[n + 1];
    int j2 = offs2[n], e2 = offs2[n + 1];
    float acc1 = 0.f, acc2 = 0.f;

    // main loop: both halves advance together, 2-way unrolled each
    // -> 4 independent load->gather->fma chains in flight
    while (j1 + 1 < e1 && j2 + 1 < e2) {
        unsigned int s0 = csrA1[j1], s1 = csrA1[j1 + 1];
        unsigned int s2 = csrA2[j2], s3 = csrA2[j2 + 1];
        float wa = __half2float(__ushort_as_half(wk1[j1]));
        float wb = __half2float(__ushort_as_half(wk1[j1 + 1]));
        float wc = __half2float(__ushort_as_half(wk2[j2]));
        float wd = __half2float(__ushort_as_half(wk2[j2 + 1]));
        float v0 = hval<IN16>(hin, s0, f);
        float v1 = hval<IN16>(hin, s1, f);
        float v2 = hval<IN16>(hin, s2, f);
        float v3 = hval<IN16>(hin, s3, f);
        acc1 = fmaf(wa, v0, acc1);
        acc1 = fmaf(wb, v1, acc1);
        acc2 = fmaf(wc, v2, acc2);
        acc2 = fmaf(wd, v3, acc2);
        j1 += 2; j2 += 2;
    }
    // drain remainders
    acc1 = seg_acc<IN16>(j1, e1, csrA1, wk1, hin, f, acc1);
    acc2 = seg_acc<IN16>(j2, e2, csrA2, wk2, hin, f, acc2);

    float acc = acc1 + acc2;
    int o = n * NFEAT + f;
    if (SIG) {
        ((float*)hout)[o] = 1.f / (1.f + expf(-2.f * acc));
    } else {
        ((unsigned short*)hout)[o] = __half_as_ushort(__float2half_rn(acc + h0[o]));
    }
}

// ---------------- fallback (atomic push path, needs only 6.4 MB ws) ----------------
__global__ __launch_bounds__(256) void scatter_layer(
    const int* __restrict__ src, const int* __restrict__ dst,
    const float* __restrict__ wt, const float* __restrict__ lw,
    const float* __restrict__ h, float* __restrict__ acc)
{
    long t = (long)blockIdx.x * blockDim.x + threadIdx.x;
    int e = (int)(t >> 4);
    if (e >= NEDGES) return;
    int f = (int)(t & 15);
    float w = wt[e] * lw[e];
    atomicAdd(&acc[dst[e] * NFEAT + f], w * h[src[e] * NFEAT + f]);
}
__global__ __launch_bounds__(256) void sigmoid_inplace(float* __restrict__ out, int n)
{
    int i = blockIdx.x * blockDim.x + threadIdx.x;
    if (i < n) out[i] = 1.f / (1.f + expf(-2.f * out[i]));
}

// ---------------- launch ----------------
extern "C" void kernel_launch(void* const* d_in, const int* in_sizes, int n_in,
                              void* d_out, int out_size, void* d_ws, size_t ws_size,
                              hipStream_t stream)
{
    const float* h0 = (const float*)d_in[0];
    const int*   ei = (const int*)d_in[1];     // int32 (JAX x64 off)
    const float* wt = (const float*)d_in[2];
    const float* lw = (const float*)d_in[3];

    const int* src = ei;
    const int* dst = ei + NEDGES;

    // workspace layout (bytes)
    const size_t off_cnt   = 0;                                 // int[125*250]
    const size_t off_tot   = 125056;
    const size_t off_bb    = 126080;
    const size_t off_offs1 = 127104;                            // int[100001]
    const size_t off_offs2 = off_offs1 + 400128;
    const size_t off_csrA  = off_offs2 + 400128;                // u32[2*EH]   12.8 MB
    const size_t off_w     = off_csrA + (size_t)2 * EH * 4;     // f16[8*EH]   25.6 MB
    const size_t off_bins  = off_w + (size_t)8 * EH * 2;        // u32[3*EH]   19.2 MB
    const size_t need      = off_bins + (size_t)3 * EH * 4;     // ~58.5 MB

    if (ws_size < need) {
        const size_t hbytes = (size_t)NNODES * NFEAT * sizeof(float);
        float* hw = (float*)d_ws;
        float* ho = (float*)d_out;
        dim3 blk(256), grd(((long)NEDGES * 16 + 255) / 256);
        hipMemcpyAsync(hw, h0, hbytes, hipMemcpyDeviceToDevice, stream);
        scatter_layer<<<grd, blk, 0, stream>>>(src, dst, wt, lw + 0L * NEDGES, h0, hw);
        hipMemcpyAsync(ho, h0, hbytes, hipMemcpyDeviceToDevice, stream);
        scatter_layer<<<grd, blk, 0, stream>>>(src, dst, wt, lw + 1L * NEDGES, hw, ho);
        hipMemcpyAsync(hw, h0, hbytes, hipMemcpyDeviceToDevice, stream);
        scatter_layer<<<grd, blk, 0, stream>>>(src, dst, wt, lw + 2L * NEDGES, ho, hw);
        hipMemsetAsync(ho, 0, hbytes, stream);
        scatter_layer<<<grd, blk, 0, stream>>>(src, dst, wt, lw + 3L * NEDGES, hw, ho);
        int n = NNODES * NFEAT;
        sigmoid_inplace<<<(n + 255) / 256, 256, 0, stream>>>(ho, n);
        return;
    }

    char* ws = (char*)d_ws;
    int*            cnt   = (int*)(ws + off_cnt);
    int*            tot   = (int*)(ws + off_tot);
    int*            bb    = (int*)(ws + off_bb);
    int*            offs1 = (int*)(ws + off_offs1);
    int*            offs2 = (int*)(ws + off_offs2);
    unsigned int*   csrA1 = (unsigned int*)(ws + off_csrA);
    unsigned int*   csrA2 = csrA1 + EH;
    unsigned short* wbase = (unsigned short*)(ws + off_w);
    unsigned short* w0_1 = wbase + 0L * EH; unsigned short* w1_1 = wbase + 1L * EH;
    unsigned short* w2_1 = wbase + 2L * EH; unsigned short* w3_1 = wbase + 3L * EH;
    unsigned short* w0_2 = wbase + 4L * EH; unsigned short* w1_2 = wbase + 5L * EH;
    unsigned short* w2_2 = wbase + 6L * EH; unsigned short* w3_2 = wbase + 7L * EH;
    unsigned int*   binsE = (unsigned int*)(ws + off_bins);
    __half*         hbA   = (__half*)(ws + off_bins);                  // alias dead bins
    __half*         hbB   = (__half*)(ws + off_bins + (size_t)NNODES * NFEAT * 2);
    float*          hout  = (float*)d_out;

    // ---- build: two independent halves ----
    // half 1
    hist_chunk  <<<NCH, 1024, 0, stream>>>(dst, 0, cnt);
    scan_chunks <<<NB,   256, 0, stream>>>(cnt, tot);
    scan_tot    <<<1,    256, 0, stream>>>(tot, bb);
    scatter_bins<<<NCH, 1024, 0, stream>>>(src, dst, wt, lw, 0, cnt, bb, binsE);
    bucket_csr  <<<NB,   512, 0, stream>>>(bb, binsE, csrA1, w0_1, w1_1, w2_1, w3_1, offs1);
    // half 2
    hist_chunk  <<<NCH, 1024, 0, stream>>>(dst, EH, cnt);
    scan_chunks <<<NB,   256, 0, stream>>>(cnt, tot);
    scan_tot    <<<1,    256, 0, stream>>>(tot, bb);
    scatter_bins<<<NCH, 1024, 0, stream>>>(src, dst, wt, lw, EH, cnt, bb, binsE);
    bucket_csr  <<<NB,   512, 0, stream>>>(bb, binsE, csrA2, w0_2, w1_2, w2_2, w3_2, offs2);

    // ---- 4 pull layers ----
    dim3 blk(256), grd((NNODES * 16) / 256);
    pull16<false, false><<<grd, blk, 0, stream>>>(offs1, offs2, csrA1, csrA2, w0_1, w0_2, h0,  h0, hbA);
    pull16<true,  false><<<grd, blk, 0, stream>>>(offs1, offs2, csrA1, csrA2, w1_1, w1_2, hbA, h0, hbB);
    pull16<true,  false><<<grd, blk, 0, stream>>>(offs1, offs2, csrA1, csrA2, w2_1, w2_2, hbB, h0, hbA);
    pull16<true,  true ><<<grd, blk, 0, stream>>>(offs1, offs2, csrA1, csrA2, w3_1, w3_2, hbA, h0, hout);
}

// Round 12
// 294.160 us; speedup vs baseline: 3.1494x; 1.2698x over previous
//
#include <hip/hip_runtime.h>
#include <hip/hip_fp16.h>

#define NNODES   100000
#define NFEAT    16
#define NEDGES   3200000
#define EH       1600000     // edges per half
#define NB       250         // dst buckets
#define NODES_PB 400         // 250*400 = 100000
#define NCH      125         // chunks per half
#define CHK      12800       // 125*12800 = 1600000
#define CAP      7168        // per-bucket-half capacity (mean 6400, sigma~80 -> +9.6s)

// ---------- K1: per-chunk bucket histogram over one half ----------
__global__ __launch_bounds__(1024) void hist_chunk(
    const int* __restrict__ dst, int ebase, int* __restrict__ cnt /*[NCH][NB]*/)
{
    __shared__ int h[NB];
    int c = blockIdx.x;
    for (int i = threadIdx.x; i < NB; i += 1024) h[i] = 0;
    __syncthreads();
    int base = ebase + c * CHK;
    for (int i = threadIdx.x; i < CHK; i += 1024) {
        int d = dst[base + i];
        atomicAdd(&h[d / NODES_PB], 1);
    }
    __syncthreads();
    for (int i = threadIdx.x; i < NB; i += 1024) cnt[c * NB + i] = h[i];
}

// ---------- K2: per-bucket exclusive scan over chunks ----------
__global__ __launch_bounds__(256) void scan_chunks(
    int* __restrict__ cnt, int* __restrict__ tot)
{
    __shared__ int x[256];
    int b = blockIdx.x, t = threadIdx.x;
    int v = (t < NCH) ? cnt[t * NB + b] : 0;
    x[t] = v;
    __syncthreads();
    for (int off = 1; off < 256; off <<= 1) {
        int y = (t >= off) ? x[t - off] : 0;
        __syncthreads();
        x[t] += y;
        __syncthreads();
    }
    if (t < NCH) cnt[t * NB + b] = x[t] - v;
    if (t == NCH - 1) tot[b] = x[t];
}

// ---------- K3: exclusive scan of bucket totals -> bb[NB+1] ----------
__global__ __launch_bounds__(256) void scan_tot(
    const int* __restrict__ tot, int* __restrict__ bb)
{
    __shared__ int x[256];
    int t = threadIdx.x;
    int v = (t < NB) ? tot[t] : 0;
    x[t] = v;
    __syncthreads();
    for (int off = 1; off < 256; off <<= 1) {
        int y = (t >= off) ? x[t - off] : 0;
        __syncthreads();
        x[t] += y;
        __syncthreads();
    }
    if (t < NB) bb[t] = x[t] - v;
    if (t == NB - 1) bb[NB] = x[t];
}

// ---------- K4: scatter edges of one half into bucket-major AoS slots ----------
// entry = 3 dwords: {src | dl<<17, half2(w0,w1), half2(w2,w3)}
__global__ __launch_bounds__(1024) void scatter_bins(
    const int*   __restrict__ src,
    const int*   __restrict__ dst,
    const float* __restrict__ wt,
    const float* __restrict__ lw,
    int ebase,
    const int*   __restrict__ cnt,
    const int*   __restrict__ bb,
    unsigned int* __restrict__ binsE)
{
    __shared__ int cur[NB];
    int c = blockIdx.x;
    for (int i = threadIdx.x; i < NB; i += 1024)
        cur[i] = bb[i] + cnt[c * NB + i];
    __syncthreads();
    int base = ebase + c * CHK;
    for (int i = threadIdx.x; i < CHK; i += 1024) {
        int e = base + i;
        int d = dst[e];
        int b  = d / NODES_PB;
        int dl = d - b * NODES_PB;
        float w = wt[e];
        __half2 w01 = __floats2half2_rn(w * lw[e],              w * lw[NEDGES + e]);
        __half2 w23 = __floats2half2_rn(w * lw[2 * NEDGES + e], w * lw[3 * NEDGES + e]);
        int slot = atomicAdd(&cur[b], 1);
        unsigned int* p = binsE + 3u * (unsigned int)slot;
        p[0] = (unsigned int)src[e] | ((unsigned int)dl << 17);
        p[1] = *(const unsigned int*)&w01;
        p[2] = *(const unsigned int*)&w23;
    }
}

// ---------- K5: per-bucket node sort, permutation in LDS, sequential flushes ----------
__global__ __launch_bounds__(512) void bucket_csr(
    const int*          __restrict__ bb,
    const unsigned int* __restrict__ binsE,
    unsigned int*       __restrict__ csrA,
    unsigned short*     __restrict__ w0,    // f16 bit patterns
    unsigned short*     __restrict__ w1,
    unsigned short*     __restrict__ w2,
    unsigned short*     __restrict__ w3,
    int*                __restrict__ offs)
{
    __shared__ unsigned int   regA[CAP];    // P1-P2b: sA ; P3-P4: {w0,w1} u16 planes
    __shared__ unsigned int   regC[CAP];    // P2-P2b: inv u16 ; P3-P4: {w2,w3} u16 planes
    __shared__ unsigned short pi[CAP];      // edge -> slot
    __shared__ int hist[NODES_PB];
    __shared__ int cur[NODES_PB];
    __shared__ int sc[512];                 // total ~75 KiB -> 2 blocks/CU
    int b  = blockIdx.x, t = threadIdx.x;
    int e0 = bb[b];
    int cnt = bb[b + 1] - e0;
    if (cnt > CAP) cnt = CAP;               // statistically impossible; guards corruption

    for (int i = t; i < NODES_PB; i += 512) hist[i] = 0;
    __syncthreads();
    // P1: stage word0 + node histogram
    for (int i = t; i < cnt; i += 512) {
        unsigned int a = binsE[3u * (unsigned int)(e0 + i)];
        regA[i] = a;
        atomicAdd(&hist[a >> 17], 1);
    }
    __syncthreads();
    // exclusive scan of 400 node counts
    int v = (t < NODES_PB) ? hist[t] : 0;
    sc[t] = v;
    __syncthreads();
    for (int off = 1; off < 512; off <<= 1) {
        int y = (t >= off) ? sc[t - off] : 0;
        __syncthreads();
        sc[t] += y;
        __syncthreads();
    }
    if (t < NODES_PB) {
        int excl = sc[t] - v;
        cur[t] = excl;
        offs[b * NODES_PB + t] = e0 + excl;
    }
    if (b == 0 && t == 0) offs[NNODES] = EH;
    __syncthreads();
    // P2: assign slots; build pi (edge->slot) and inv (slot->edge) in LDS
    unsigned short* inv = (unsigned short*)regC;
    for (int i = t; i < cnt; i += 512) {
        unsigned int a = regA[i];
        int slot = atomicAdd(&cur[a >> 17], 1);
        pi[i]  = (unsigned short)slot;
        inv[slot] = (unsigned short)i;
    }
    __syncthreads();
    // P2b: flush csrA SEQUENTIALLY (gather via inv)
    for (int s = t; s < cnt; s += 512) {
        csrA[e0 + s] = regA[inv[s]] & 0x1FFFFu;
    }
    __syncthreads();
    // P3: read weight words once; scatter f16 halves into LDS planes at pi[i]
    unsigned short* wA0 = (unsigned short*)regA;         // overwrites dead sA
    unsigned short* wA1 = wA0 + CAP;
    unsigned short* wC2 = (unsigned short*)regC;         // overwrites dead inv
    unsigned short* wC3 = wC2 + CAP;
    for (int i = t; i < cnt; i += 512) {
        unsigned int u01 = binsE[3u * (unsigned int)(e0 + i) + 1];
        unsigned int u23 = binsE[3u * (unsigned int)(e0 + i) + 2];
        int s = pi[i];
        wA0[s] = (unsigned short)(u01 & 0xFFFFu);
        wA1[s] = (unsigned short)(u01 >> 16);
        wC2[s] = (unsigned short)(u23 & 0xFFFFu);
        wC3[s] = (unsigned short)(u23 >> 16);
    }
    __syncthreads();
    // P4: flush all four planes SEQUENTIALLY
    for (int s = t; s < cnt; s += 512) {
        w0[e0 + s] = wA0[s];
        w1[e0 + s] = wA1[s];
        w2[e0 + s] = wC2[s];
        w3[e0 + s] = wC3[s];
    }
}

// ---------- helpers ----------
template<bool IN16>
__device__ __forceinline__ float hval(const void* __restrict__ hin, unsigned int s, int f)
{
    if (IN16) return __half2float(((const __half*)hin)[s * NFEAT + f]);
    else      return ((const float*)hin)[s * NFEAT + f];
}

template<bool IN16>
__device__ __forceinline__ float seg_acc(
    int j, int j1, const unsigned int* __restrict__ csrA,
    const unsigned short* __restrict__ wku, const void* __restrict__ hin,
    int f, float acc)
{
    for (; j + 1 < j1; j += 2) {
        unsigned int s0 = csrA[j], s1 = csrA[j + 1];
        float wa = __half2float(__ushort_as_half(wku[j]));
        float wb = __half2float(__ushort_as_half(wku[j + 1]));
        float v0 = hval<IN16>(hin, s0, f);
        float v1 = hval<IN16>(hin, s1, f);
        acc = fmaf(wa, v0, acc);
        acc = fmaf(wb, v1, acc);
    }
    if (j < j1) {
        unsigned int s0 = csrA[j];
        float wa = __half2float(__ushort_as_half(wku[j]));
        acc = fmaf(wa, hval<IN16>(hin, s0, f), acc);
    }
    return acc;
}

// ---------- K6: pull layer — both halves interleaved: 4 independent chains ----------
template<bool IN16, bool SIG>
__global__ __launch_bounds__(256) void pull16(
    const int*            __restrict__ offs1,
    const int*            __restrict__ offs2,
    const unsigned int*   __restrict__ csrA1,
    const unsigned int*   __restrict__ csrA2,
    const unsigned short* __restrict__ wk1,
    const unsigned short* __restrict__ wk2,
    const void*           __restrict__ hin,
    const float*          __restrict__ h0,
    void*                 __restrict__ hout)
{
    int t = blockIdx.x * 256 + threadIdx.x;
    int n = t >> 4;
    if (n >= NNODES) return;
    int f = t & 15;
    int j1 = offs1[n], e1 = offs1[n + 1];
    int j2 = offs2[n], e2 = offs2[n + 1];
    float acc1 = 0.f, acc2 = 0.f;

    while (j1 + 1 < e1 && j2 + 1 < e2) {
        unsigned int s0 = csrA1[j1], s1 = csrA1[j1 + 1];
        unsigned int s2 = csrA2[j2], s3 = csrA2[j2 + 1];
        float wa = __half2float(__ushort_as_half(wk1[j1]));
        float wb = __half2float(__ushort_as_half(wk1[j1 + 1]));
        float wc = __half2float(__ushort_as_half(wk2[j2]));
        float wd = __half2float(__ushort_as_half(wk2[j2 + 1]));
        float v0 = hval<IN16>(hin, s0, f);
        float v1 = hval<IN16>(hin, s1, f);
        float v2 = hval<IN16>(hin, s2, f);
        float v3 = hval<IN16>(hin, s3, f);
        acc1 = fmaf(wa, v0, acc1);
        acc1 = fmaf(wb, v1, acc1);
        acc2 = fmaf(wc, v2, acc2);
        acc2 = fmaf(wd, v3, acc2);
        j1 += 2; j2 += 2;
    }
    acc1 = seg_acc<IN16>(j1, e1, csrA1, wk1, hin, f, acc1);
    acc2 = seg_acc<IN16>(j2, e2, csrA2, wk2, hin, f, acc2);

    float acc = acc1 + acc2;
    int o = n * NFEAT + f;
    if (SIG) {
        ((float*)hout)[o] = 1.f / (1.f + expf(-2.f * acc));
    } else {
        ((unsigned short*)hout)[o] = __half_as_ushort(__float2half_rn(acc + h0[o]));
    }
}

// ---------------- fallback (atomic push path, needs only 6.4 MB ws) ----------------
__global__ __launch_bounds__(256) void scatter_layer(
    const int* __restrict__ src, const int* __restrict__ dst,
    const float* __restrict__ wt, const float* __restrict__ lw,
    const float* __restrict__ h, float* __restrict__ acc)
{
    long t = (long)blockIdx.x * blockDim.x + threadIdx.x;
    int e = (int)(t >> 4);
    if (e >= NEDGES) return;
    int f = (int)(t & 15);
    float w = wt[e] * lw[e];
    atomicAdd(&acc[dst[e] * NFEAT + f], w * h[src[e] * NFEAT + f]);
}
__global__ __launch_bounds__(256) void sigmoid_inplace(float* __restrict__ out, int n)
{
    int i = blockIdx.x * blockDim.x + threadIdx.x;
    if (i < n) out[i] = 1.f / (1.f + expf(-2.f * out[i]));
}

// ---------------- launch ----------------
extern "C" void kernel_launch(void* const* d_in, const int* in_sizes, int n_in,
                              void* d_out, int out_size, void* d_ws, size_t ws_size,
                              hipStream_t stream)
{
    const float* h0 = (const float*)d_in[0];
    const int*   ei = (const int*)d_in[1];     // int32 (JAX x64 off)
    const float* wt = (const float*)d_in[2];
    const float* lw = (const float*)d_in[3];

    const int* src = ei;
    const int* dst = ei + NEDGES;

    // workspace layout (bytes)
    const size_t off_cnt   = 0;                                 // int[125*250]
    const size_t off_tot   = 125056;
    const size_t off_bb    = 126080;
    const size_t off_offs1 = 127104;                            // int[100001]
    const size_t off_offs2 = off_offs1 + 400128;
    const size_t off_csrA  = off_offs2 + 400128;                // u32[2*EH]   12.8 MB
    const size_t off_w     = off_csrA + (size_t)2 * EH * 4;     // f16[8*EH]   25.6 MB
    const size_t off_bins  = off_w + (size_t)8 * EH * 2;        // u32[3*EH]   19.2 MB
    const size_t need      = off_bins + (size_t)3 * EH * 4;     // ~58.5 MB

    if (ws_size < need) {
        const size_t hbytes = (size_t)NNODES * NFEAT * sizeof(float);
        float* hw = (float*)d_ws;
        float* ho = (float*)d_out;
        dim3 blk(256), grd(((long)NEDGES * 16 + 255) / 256);
        hipMemcpyAsync(hw, h0, hbytes, hipMemcpyDeviceToDevice, stream);
        scatter_layer<<<grd, blk, 0, stream>>>(src, dst, wt, lw + 0L * NEDGES, h0, hw);
        hipMemcpyAsync(ho, h0, hbytes, hipMemcpyDeviceToDevice, stream);
        scatter_layer<<<grd, blk, 0, stream>>>(src, dst, wt, lw + 1L * NEDGES, hw, ho);
        hipMemcpyAsync(hw, h0, hbytes, hipMemcpyDeviceToDevice, stream);
        scatter_layer<<<grd, blk, 0, stream>>>(src, dst, wt, lw + 2L * NEDGES, ho, hw);
        hipMemsetAsync(ho, 0, hbytes, stream);
        scatter_layer<<<grd, blk, 0, stream>>>(src, dst, wt, lw + 3L * NEDGES, hw, ho);
        int n = NNODES * NFEAT;
        sigmoid_inplace<<<(n + 255) / 256, 256, 0, stream>>>(ho, n);
        return;
    }

    char* ws = (char*)d_ws;
    int*            cnt   = (int*)(ws + off_cnt);
    int*            tot   = (int*)(ws + off_tot);
    int*            bb    = (int*)(ws + off_bb);
    int*            offs1 = (int*)(ws + off_offs1);
    int*            offs2 = (int*)(ws + off_offs2);
    unsigned int*   csrA1 = (unsigned int*)(ws + off_csrA);
    unsigned int*   csrA2 = csrA1 + EH;
    unsigned short* wbase = (unsigned short*)(ws + off_w);
    unsigned short* w0_1 = wbase + 0L * EH; unsigned short* w1_1 = wbase + 1L * EH;
    unsigned short* w2_1 = wbase + 2L * EH; unsigned short* w3_1 = wbase + 3L * EH;
    unsigned short* w0_2 = wbase + 4L * EH; unsigned short* w1_2 = wbase + 5L * EH;
    unsigned short* w2_2 = wbase + 6L * EH; unsigned short* w3_2 = wbase + 7L * EH;
    unsigned int*   binsE = (unsigned int*)(ws + off_bins);
    __half*         hbA   = (__half*)(ws + off_bins);                  // alias dead bins
    __half*         hbB   = (__half*)(ws + off_bins + (size_t)NNODES * NFEAT * 2);
    float*          hout  = (float*)d_out;

    // ---- build: two independent halves ----
    // half 1
    hist_chunk  <<<NCH, 1024, 0, stream>>>(dst, 0, cnt);
    scan_chunks <<<NB,   256, 0, stream>>>(cnt, tot);
    scan_tot    <<<1,    256, 0, stream>>>(tot, bb);
    scatter_bins<<<NCH, 1024, 0, stream>>>(src, dst, wt, lw, 0, cnt, bb, binsE);
    bucket_csr  <<<NB,   512, 0, stream>>>(bb, binsE, csrA1, w0_1, w1_1, w2_1, w3_1, offs1);
    // half 2
    hist_chunk  <<<NCH, 1024, 0, stream>>>(dst, EH, cnt);
    scan_chunks <<<NB,   256, 0, stream>>>(cnt, tot);
    scan_tot    <<<1,    256, 0, stream>>>(tot, bb);
    scatter_bins<<<NCH, 1024, 0, stream>>>(src, dst, wt, lw, EH, cnt, bb, binsE);
    bucket_csr  <<<NB,   512, 0, stream>>>(bb, binsE, csrA2, w0_2, w1_2, w2_2, w3_2, offs2);

    // ---- 4 pull layers ----
    dim3 blk(256), grd((NNODES * 16) / 256);
    pull16<false, false><<<grd, blk, 0, stream>>>(offs1, offs2, csrA1, csrA2, w0_1, w0_2, h0,  h0, hbA);
    pull16<true,  false><<<grd, blk, 0, stream>>>(offs1, offs2, csrA1, csrA2, w1_1, w1_2, hbA, h0, hbB);
    pull16<true,  false><<<grd, blk, 0, stream>>>(offs1, offs2, csrA1, csrA2, w2_1, w2_2, hbB, h0, hbA);
    pull16<true,  true ><<<grd, blk, 0, stream>>>(offs1, offs2, csrA1, csrA2, w3_1, w3_2, hbA, h0, hout);
}

// Round 13
// 277.029 us; speedup vs baseline: 3.3441x; 1.0618x over previous
//
#include <hip/hip_runtime.h>
#include <hip/hip_fp16.h>

#define NNODES   100000
#define NFEAT    16
#define NEDGES   3200000
#define EH       1600000     // edges per half
#define NB       250         // dst buckets
#define NODES_PB 400         // 250*400 = 100000
#define NCH      125         // chunks per half
#define CHK      12800       // 125*12800 = 1600000
#define CAP      7168        // per-bucket-half capacity (mean 6400, sigma~80 -> +9.6s)

// ---------- K1: per-chunk bucket histogram over one half ----------
__global__ __launch_bounds__(1024) void hist_chunk(
    const int* __restrict__ dst, int ebase, int* __restrict__ cnt /*[NCH][NB]*/)
{
    __shared__ int h[NB];
    int c = blockIdx.x;
    for (int i = threadIdx.x; i < NB; i += 1024) h[i] = 0;
    __syncthreads();
    int base = ebase + c * CHK;
    for (int i = threadIdx.x; i < CHK; i += 1024) {
        int d = dst[base + i];
        atomicAdd(&h[d / NODES_PB], 1);
    }
    __syncthreads();
    for (int i = threadIdx.x; i < NB; i += 1024) cnt[c * NB + i] = h[i];
}

// ---------- K2: per-bucket exclusive scan over chunks ----------
__global__ __launch_bounds__(256) void scan_chunks(
    int* __restrict__ cnt, int* __restrict__ tot)
{
    __shared__ int x[256];
    int b = blockIdx.x, t = threadIdx.x;
    int v = (t < NCH) ? cnt[t * NB + b] : 0;
    x[t] = v;
    __syncthreads();
    for (int off = 1; off < 256; off <<= 1) {
        int y = (t >= off) ? x[t - off] : 0;
        __syncthreads();
        x[t] += y;
        __syncthreads();
    }
    if (t < NCH) cnt[t * NB + b] = x[t] - v;
    if (t == NCH - 1) tot[b] = x[t];
}

// ---------- K3: exclusive scan of bucket totals -> bb[NB+1] ----------
__global__ __launch_bounds__(256) void scan_tot(
    const int* __restrict__ tot, int* __restrict__ bb)
{
    __shared__ int x[256];
    int t = threadIdx.x;
    int v = (t < NB) ? tot[t] : 0;
    x[t] = v;
    __syncthreads();
    for (int off = 1; off < 256; off <<= 1) {
        int y = (t >= off) ? x[t - off] : 0;
        __syncthreads();
        x[t] += y;
        __syncthreads();
    }
    if (t < NB) bb[t] = x[t] - v;
    if (t == NB - 1) bb[NB] = x[t];
}

// ---------- K4: scatter edges of one half into bucket-major AoS slots ----------
// entry = 3 dwords: {src | dl<<17, half2(w0,w1), half2(w2,w3)}
__global__ __launch_bounds__(1024) void scatter_bins(
    const int*   __restrict__ src,
    const int*   __restrict__ dst,
    const float* __restrict__ wt,
    const float* __restrict__ lw,
    int ebase,
    const int*   __restrict__ cnt,
    const int*   __restrict__ bb,
    unsigned int* __restrict__ binsE)
{
    __shared__ int cur[NB];
    int c = blockIdx.x;
    for (int i = threadIdx.x; i < NB; i += 1024)
        cur[i] = bb[i] + cnt[c * NB + i];
    __syncthreads();
    int base = ebase + c * CHK;
    for (int i = threadIdx.x; i < CHK; i += 1024) {
        int e = base + i;
        int d = dst[e];
        int b  = d / NODES_PB;
        int dl = d - b * NODES_PB;
        float w = wt[e];
        __half2 w01 = __floats2half2_rn(w * lw[e],              w * lw[NEDGES + e]);
        __half2 w23 = __floats2half2_rn(w * lw[2 * NEDGES + e], w * lw[3 * NEDGES + e]);
        int slot = atomicAdd(&cur[b], 1);
        unsigned int* p = binsE + 3u * (unsigned int)slot;
        p[0] = (unsigned int)src[e] | ((unsigned int)dl << 17);
        p[1] = *(const unsigned int*)&w01;
        p[2] = *(const unsigned int*)&w23;
    }
}

// ---------- K5: per-bucket node sort, permutation in LDS, sequential flushes ----------
__global__ __launch_bounds__(512) void bucket_csr(
    const int*          __restrict__ bb,
    const unsigned int* __restrict__ binsE,
    unsigned int*       __restrict__ csrA,
    unsigned short*     __restrict__ w0,    // f16 bit patterns
    unsigned short*     __restrict__ w1,
    unsigned short*     __restrict__ w2,
    unsigned short*     __restrict__ w3,
    int*                __restrict__ offs)
{
    __shared__ unsigned int   regA[CAP];    // P1-P2b: sA ; P3-P4: {w0,w1} u16 planes
    __shared__ unsigned int   regC[CAP];    // P2-P2b: inv u16 ; P3-P4: {w2,w3} u16 planes
    __shared__ unsigned short pi[CAP];      // edge -> slot
    __shared__ int hist[NODES_PB];
    __shared__ int cur[NODES_PB];
    __shared__ int sc[512];                 // total ~75 KiB -> 2 blocks/CU
    int b  = blockIdx.x, t = threadIdx.x;
    int e0 = bb[b];
    int cnt = bb[b + 1] - e0;
    if (cnt > CAP) cnt = CAP;               // statistically impossible; guards corruption

    for (int i = t; i < NODES_PB; i += 512) hist[i] = 0;
    __syncthreads();
    // P1: stage word0 + node histogram
    for (int i = t; i < cnt; i += 512) {
        unsigned int a = binsE[3u * (unsigned int)(e0 + i)];
        regA[i] = a;
        atomicAdd(&hist[a >> 17], 1);
    }
    __syncthreads();
    // exclusive scan of 400 node counts
    int v = (t < NODES_PB) ? hist[t] : 0;
    sc[t] = v;
    __syncthreads();
    for (int off = 1; off < 512; off <<= 1) {
        int y = (t >= off) ? sc[t - off] : 0;
        __syncthreads();
        sc[t] += y;
        __syncthreads();
    }
    if (t < NODES_PB) {
        int excl = sc[t] - v;
        cur[t] = excl;
        offs[b * NODES_PB + t] = e0 + excl;
    }
    if (b == 0 && t == 0) offs[NNODES] = EH;
    __syncthreads();
    // P2: assign slots; build pi (edge->slot) and inv (slot->edge) in LDS
    unsigned short* inv = (unsigned short*)regC;
    for (int i = t; i < cnt; i += 512) {
        unsigned int a = regA[i];
        int slot = atomicAdd(&cur[a >> 17], 1);
        pi[i]  = (unsigned short)slot;
        inv[slot] = (unsigned short)i;
    }
    __syncthreads();
    // P2b: flush csrA SEQUENTIALLY (gather via inv)
    for (int s = t; s < cnt; s += 512) {
        csrA[e0 + s] = regA[inv[s]] & 0x1FFFFu;
    }
    __syncthreads();
    // P3: read weight words once; scatter f16 halves into LDS planes at pi[i]
    unsigned short* wA0 = (unsigned short*)regA;         // overwrites dead sA
    unsigned short* wA1 = wA0 + CAP;
    unsigned short* wC2 = (unsigned short*)regC;         // overwrites dead inv
    unsigned short* wC3 = wC2 + CAP;
    for (int i = t; i < cnt; i += 512) {
        unsigned int u01 = binsE[3u * (unsigned int)(e0 + i) + 1];
        unsigned int u23 = binsE[3u * (unsigned int)(e0 + i) + 2];
        int s = pi[i];
        wA0[s] = (unsigned short)(u01 & 0xFFFFu);
        wA1[s] = (unsigned short)(u01 >> 16);
        wC2[s] = (unsigned short)(u23 & 0xFFFFu);
        wC3[s] = (unsigned short)(u23 >> 16);
    }
    __syncthreads();
    // P4: flush all four planes SEQUENTIALLY
    for (int s = t; s < cnt; s += 512) {
        w0[e0 + s] = wA0[s];
        w1[e0 + s] = wA1[s];
        w2[e0 + s] = wC2[s];
        w3[e0 + s] = wC3[s];
    }
}

// ---------- K5b: convert h0 (f32) -> f16 table ----------
__global__ __launch_bounds__(256) void conv16(
    const float2* __restrict__ in, __half2* __restrict__ out, int n2)
{
    int i = blockIdx.x * 256 + threadIdx.x;
    if (i < n2) {
        float2 v = in[i];
        out[i] = __floats2half2_rn(v.x, v.y);
    }
}

// ---------- helpers ----------
__device__ __forceinline__ float hval16(const __half* __restrict__ h16, unsigned int s, int f)
{
    return __half2float(h16[s * NFEAT + f]);
}

__device__ __forceinline__ float seg_acc16(
    int j, int j1, const unsigned int* __restrict__ csrA,
    const unsigned short* __restrict__ wku, const __half* __restrict__ h16,
    int f, float acc)
{
    for (; j + 1 < j1; j += 2) {
        unsigned int s0 = csrA[j], s1 = csrA[j + 1];
        float wa = __half2float(__ushort_as_half(wku[j]));
        float wb = __half2float(__ushort_as_half(wku[j + 1]));
        acc = fmaf(wa, hval16(h16, s0, f), acc);
        acc = fmaf(wb, hval16(h16, s1, f), acc);
    }
    if (j < j1) {
        unsigned int s0 = csrA[j];
        float wa = __half2float(__ushort_as_half(wku[j]));
        acc = fmaf(wa, hval16(h16, s0, f), acc);
    }
    return acc;
}

// ---------- K6: pull layer — 8 independent load->gather->fma chains ----------
template<bool SIG>
__global__ __launch_bounds__(256) void pull16(
    const int*            __restrict__ offs1,
    const int*            __restrict__ offs2,
    const unsigned int*   __restrict__ csrA1,
    const unsigned int*   __restrict__ csrA2,
    const unsigned short* __restrict__ wk1,
    const unsigned short* __restrict__ wk2,
    const __half*         __restrict__ h16,
    const float*          __restrict__ h0,
    void*                 __restrict__ hout)
{
    int t = blockIdx.x * 256 + threadIdx.x;
    int n = t >> 4;
    if (n >= NNODES) return;
    int f = t & 15;
    int j1 = offs1[n], e1 = offs1[n + 1];
    int j2 = offs2[n], e2 = offs2[n + 1];
    float acc1 = 0.f, acc2 = 0.f;

    // 8-chain main loop: 4 edges from each half per iteration
    while (j1 + 3 < e1 && j2 + 3 < e2) {
        unsigned int s0 = csrA1[j1],     s1 = csrA1[j1 + 1];
        unsigned int s2 = csrA1[j1 + 2], s3 = csrA1[j1 + 3];
        unsigned int s4 = csrA2[j2],     s5 = csrA2[j2 + 1];
        unsigned int s6 = csrA2[j2 + 2], s7 = csrA2[j2 + 3];
        float wa = __half2float(__ushort_as_half(wk1[j1]));
        float wb = __half2float(__ushort_as_half(wk1[j1 + 1]));
        float wc = __half2float(__ushort_as_half(wk1[j1 + 2]));
        float wd = __half2float(__ushort_as_half(wk1[j1 + 3]));
        float we = __half2float(__ushort_as_half(wk2[j2]));
        float wf = __half2float(__ushort_as_half(wk2[j2 + 1]));
        float wg = __half2float(__ushort_as_half(wk2[j2 + 2]));
        float wh = __half2float(__ushort_as_half(wk2[j2 + 3]));
        float v0 = hval16(h16, s0, f);
        float v1 = hval16(h16, s1, f);
        float v2 = hval16(h16, s2, f);
        float v3 = hval16(h16, s3, f);
        float v4 = hval16(h16, s4, f);
        float v5 = hval16(h16, s5, f);
        float v6 = hval16(h16, s6, f);
        float v7 = hval16(h16, s7, f);
        acc1 = fmaf(wa, v0, acc1);
        acc1 = fmaf(wb, v1, acc1);
        acc1 = fmaf(wc, v2, acc1);
        acc1 = fmaf(wd, v3, acc1);
        acc2 = fmaf(we, v4, acc2);
        acc2 = fmaf(wf, v5, acc2);
        acc2 = fmaf(wg, v6, acc2);
        acc2 = fmaf(wh, v7, acc2);
        j1 += 4; j2 += 4;
    }
    // 4-chain tail loop
    while (j1 + 1 < e1 && j2 + 1 < e2) {
        unsigned int s0 = csrA1[j1], s1 = csrA1[j1 + 1];
        unsigned int s2 = csrA2[j2], s3 = csrA2[j2 + 1];
        float wa = __half2float(__ushort_as_half(wk1[j1]));
        float wb = __half2float(__ushort_as_half(wk1[j1 + 1]));
        float wc = __half2float(__ushort_as_half(wk2[j2]));
        float wd = __half2float(__ushort_as_half(wk2[j2 + 1]));
        acc1 = fmaf(wa, hval16(h16, s0, f), acc1);
        acc1 = fmaf(wb, hval16(h16, s1, f), acc1);
        acc2 = fmaf(wc, hval16(h16, s2, f), acc2);
        acc2 = fmaf(wd, hval16(h16, s3, f), acc2);
        j1 += 2; j2 += 2;
    }
    // drain remainders
    acc1 = seg_acc16(j1, e1, csrA1, wk1, h16, f, acc1);
    acc2 = seg_acc16(j2, e2, csrA2, wk2, h16, f, acc2);

    float acc = acc1 + acc2;
    int o = n * NFEAT + f;
    if (SIG) {
        ((float*)hout)[o] = 1.f / (1.f + expf(-2.f * acc));
    } else {
        ((unsigned short*)hout)[o] = __half_as_ushort(__float2half_rn(acc + h0[o]));
    }
}

// ---------------- fallback (atomic push path, needs only 6.4 MB ws) ----------------
__global__ __launch_bounds__(256) void scatter_layer(
    const int* __restrict__ src, const int* __restrict__ dst,
    const float* __restrict__ wt, const float* __restrict__ lw,
    const float* __restrict__ h, float* __restrict__ acc)
{
    long t = (long)blockIdx.x * blockDim.x + threadIdx.x;
    int e = (int)(t >> 4);
    if (e >= NEDGES) return;
    int f = (int)(t & 15);
    float w = wt[e] * lw[e];
    atomicAdd(&acc[dst[e] * NFEAT + f], w * h[src[e] * NFEAT + f]);
}
__global__ __launch_bounds__(256) void sigmoid_inplace(float* __restrict__ out, int n)
{
    int i = blockIdx.x * blockDim.x + threadIdx.x;
    if (i < n) out[i] = 1.f / (1.f + expf(-2.f * out[i]));
}

// ---------------- launch ----------------
extern "C" void kernel_launch(void* const* d_in, const int* in_sizes, int n_in,
                              void* d_out, int out_size, void* d_ws, size_t ws_size,
                              hipStream_t stream)
{
    const float* h0 = (const float*)d_in[0];
    const int*   ei = (const int*)d_in[1];     // int32 (JAX x64 off)
    const float* wt = (const float*)d_in[2];
    const float* lw = (const float*)d_in[3];

    const int* src = ei;
    const int* dst = ei + NEDGES;

    // workspace layout (bytes)
    const size_t off_cnt   = 0;                                 // int[125*250]
    const size_t off_tot   = 125056;
    const size_t off_bb    = 126080;
    const size_t off_offs1 = 127104;                            // int[100001]
    const size_t off_offs2 = off_offs1 + 400128;
    const size_t off_csrA  = off_offs2 + 400128;                // u32[2*EH]   12.8 MB
    const size_t off_w     = off_csrA + (size_t)2 * EH * 4;     // f16[8*EH]   25.6 MB
    const size_t off_bins  = off_w + (size_t)8 * EH * 2;        // u32[3*EH]   19.2 MB
    const size_t need      = off_bins + (size_t)3 * EH * 4;     // ~58.5 MB

    if (ws_size < need) {
        const size_t hbytes = (size_t)NNODES * NFEAT * sizeof(float);
        float* hw = (float*)d_ws;
        float* ho = (float*)d_out;
        dim3 blk(256), grd(((long)NEDGES * 16 + 255) / 256);
        hipMemcpyAsync(hw, h0, hbytes, hipMemcpyDeviceToDevice, stream);
        scatter_layer<<<grd, blk, 0, stream>>>(src, dst, wt, lw + 0L * NEDGES, h0, hw);
        hipMemcpyAsync(ho, h0, hbytes, hipMemcpyDeviceToDevice, stream);
        scatter_layer<<<grd, blk, 0, stream>>>(src, dst, wt, lw + 1L * NEDGES, hw, ho);
        hipMemcpyAsync(hw, h0, hbytes, hipMemcpyDeviceToDevice, stream);
        scatter_layer<<<grd, blk, 0, stream>>>(src, dst, wt, lw + 2L * NEDGES, ho, hw);
        hipMemsetAsync(ho, 0, hbytes, stream);
        scatter_layer<<<grd, blk, 0, stream>>>(src, dst, wt, lw + 3L * NEDGES, hw, ho);
        int n = NNODES * NFEAT;
        sigmoid_inplace<<<(n + 255) / 256, 256, 0, stream>>>(ho, n);
        return;
    }

    char* ws = (char*)d_ws;
    int*            cnt   = (int*)(ws + off_cnt);
    int*            tot   = (int*)(ws + off_tot);
    int*            bb    = (int*)(ws + off_bb);
    int*            offs1 = (int*)(ws + off_offs1);
    int*            offs2 = (int*)(ws + off_offs2);
    unsigned int*   csrA1 = (unsigned int*)(ws + off_csrA);
    unsigned int*   csrA2 = csrA1 + EH;
    unsigned short* wbase = (unsigned short*)(ws + off_w);
    unsigned short* w0_1 = wbase + 0L * EH; unsigned short* w1_1 = wbase + 1L * EH;
    unsigned short* w2_1 = wbase + 2L * EH; unsigned short* w3_1 = wbase + 3L * EH;
    unsigned short* w0_2 = wbase + 4L * EH; unsigned short* w1_2 = wbase + 5L * EH;
    unsigned short* w2_2 = wbase + 6L * EH; unsigned short* w3_2 = wbase + 7L * EH;
    unsigned int*   binsE = (unsigned int*)(ws + off_bins);
    // aliases over the dead bins region (alive only after both bucket_csr calls)
    __half*         hb0   = (__half*)(ws + off_bins);                                  // f16(h0)
    __half*         hbA   = (__half*)(ws + off_bins + 1 * (size_t)NNODES * NFEAT * 2); // ping
    __half*         hbB   = (__half*)(ws + off_bins + 2 * (size_t)NNODES * NFEAT * 2); // pong
    float*          hout  = (float*)d_out;

    // ---- build: two independent halves ----
    // half 1
    hist_chunk  <<<NCH, 1024, 0, stream>>>(dst, 0, cnt);
    scan_chunks <<<NB,   256, 0, stream>>>(cnt, tot);
    scan_tot    <<<1,    256, 0, stream>>>(tot, bb);
    scatter_bins<<<NCH, 1024, 0, stream>>>(src, dst, wt, lw, 0, cnt, bb, binsE);
    bucket_csr  <<<NB,   512, 0, stream>>>(bb, binsE, csrA1, w0_1, w1_1, w2_1, w3_1, offs1);
    // half 2
    hist_chunk  <<<NCH, 1024, 0, stream>>>(dst, EH, cnt);
    scan_chunks <<<NB,   256, 0, stream>>>(cnt, tot);
    scan_tot    <<<1,    256, 0, stream>>>(tot, bb);
    scatter_bins<<<NCH, 1024, 0, stream>>>(src, dst, wt, lw, EH, cnt, bb, binsE);
    bucket_csr  <<<NB,   512, 0, stream>>>(bb, binsE, csrA2, w0_2, w1_2, w2_2, w3_2, offs2);

    // ---- convert h0 to f16 (bins region now dead) ----
    int n2 = NNODES * NFEAT / 2;
    conv16<<<(n2 + 255) / 256, 256, 0, stream>>>((const float2*)h0, (__half2*)hb0, n2);

    // ---- 4 pull layers (all-f16 gathers, 8 chains) ----
    dim3 blk(256), grd((NNODES * 16) / 256);
    pull16<false><<<grd, blk, 0, stream>>>(offs1, offs2, csrA1, csrA2, w0_1, w0_2, hb0, h0, hbA);
    pull16<false><<<grd, blk, 0, stream>>>(offs1, offs2, csrA1, csrA2, w1_1, w1_2, hbA, h0, hbB);
    pull16<false><<<grd, blk, 0, stream>>>(offs1, offs2, csrA1, csrA2, w2_1, w2_2, hbB, h0, hbA);
    pull16<true ><<<grd, blk, 0, stream>>>(offs1, offs2, csrA1, csrA2, w3_1, w3_2, hbA, h0, hout);
}